// Round 7
// baseline (249.528 us; speedup 1.0000x reference)
//
#include <hip/hip_runtime.h>

// Problem constants
constexpr int Bb = 16;      // batch
constexpr int Nn = 256;     // regions
constexpr int Hh = 768;     // hidden
constexpr int Pp = 2048;    // proj dim
constexpr int Rr = 3;       // relation types
constexpr int Mm = Bb * Nn; // 4096 flattened rows
constexpr int HA = 896;     // augmented hidden (768 + 1 bias row + pad)
constexpr int KA = 2080;    // augmented K for Bop GEMM (2048 + 32)
constexpr int JA = Rr * HA; // 2688

typedef __bf16 bf16_t;
typedef __bf16 bf16x8 __attribute__((ext_vector_type(8)));
typedef __bf16 bf16x4 __attribute__((ext_vector_type(4)));
typedef float  floatx4 __attribute__((ext_vector_type(4)));

// async global->LDS, 16B per lane; LDS dest = wave-uniform base + lane*16
__device__ __forceinline__ void gld_lds16(const void* g, void* l) {
    __builtin_amdgcn_global_load_lds(
        (__attribute__((address_space(1))) void*)g,
        (__attribute__((address_space(3))) void*)l,
        16, 0, 0);
}

// ---------------------------------------------------------------------------
// bil_W fp32 [3,2048,2048] -> bf16 (halves T1's dominant staged-byte stream).
// ---------------------------------------------------------------------------
__global__ __launch_bounds__(256) void cvt_bilW(
    const float* __restrict__ in, bf16_t* __restrict__ out)
{
    const size_t i = (size_t)blockIdx.x * 256 + threadIdx.x; // over 3*2048*2048/8
    const float4 v0 = ((const float4*)in)[2 * i];
    const float4 v1 = ((const float4*)in)[2 * i + 1];
    bf16x8 o = { (bf16_t)v0.x, (bf16_t)v0.y, (bf16_t)v0.z, (bf16_t)v0.w,
                 (bf16_t)v1.x, (bf16_t)v1.y, (bf16_t)v1.z, (bf16_t)v1.w };
    ((bf16x8*)out)[i] = o;
}

// ---------------------------------------------------------------------------
// F_aug [4096, 896] bf16: cols 0..767 = F, col 768 = 1, cols 769..895 = 0
// ---------------------------------------------------------------------------
__global__ __launch_bounds__(256) void build_Faug(
    const float* __restrict__ F, bf16_t* __restrict__ out)
{
    const int idx = blockIdx.x * 256 + threadIdx.x;   // over 4096 * (896/4)
    const int n = idx / (HA / 4), c4 = idx % (HA / 4);
    const int h = c4 * 4;
    bf16x4 o;
    if (h < Hh) {
        float4 v = *(const float4*)(F + (size_t)n * Hh + h);
        o = { (bf16_t)v.x, (bf16_t)v.y, (bf16_t)v.z, (bf16_t)v.w };
    } else {
        #pragma unroll
        for (int e = 0; e < 4; ++e) o[e] = (bf16_t)((h + e == Hh) ? 1.0f : 0.0f);
    }
    *(bf16x4*)(out + (size_t)n * HA + h) = o;
}

// ---------------------------------------------------------------------------
// tWaug [896, 2048]: rows j<768 = tW^T (tW[q,j]), row 768 = bt[q], rows>768 = 0
// ---------------------------------------------------------------------------
__global__ __launch_bounds__(256) void build_tWaug(
    const float* __restrict__ tW, const float* __restrict__ bt,
    bf16_t* __restrict__ out)
{
    __shared__ float t[32][33];
    const int j0 = blockIdx.y * 32, q0 = blockIdx.x * 32;
    const int tx = threadIdx.x, ty = threadIdx.y;
    #pragma unroll
    for (int s = 0; s < 4; ++s) {
        const int q = q0 + ty + s * 8, j = j0 + tx;
        t[ty + s * 8][tx] = (j < Hh) ? tW[(size_t)q * Hh + j] : 0.0f;
    }
    __syncthreads();
    #pragma unroll
    for (int s = 0; s < 4; ++s) {
        const int j = j0 + ty + s * 8, q = q0 + tx;
        float v = t[tx][ty + s * 8];
        if (j == Hh) v = bt[q];
        else if (j > Hh) v = 0.0f;
        out[(size_t)j * Pp + q] = (bf16_t)v;
    }
}

// ---------------------------------------------------------------------------
// hWaug [896, 2080]: rows h<768 = hW^T, row 768 = [bh | 1 @ p=2048], rows>768=0
// ---------------------------------------------------------------------------
__global__ __launch_bounds__(256) void build_hWaug(
    const float* __restrict__ hW, const float* __restrict__ bh,
    bf16_t* __restrict__ out)
{
    __shared__ float t[32][33];
    const int h0 = blockIdx.y * 32, p0 = blockIdx.x * 32;
    const int tx = threadIdx.x, ty = threadIdx.y;
    #pragma unroll
    for (int s = 0; s < 4; ++s) {
        const int p = p0 + ty + s * 8, h = h0 + tx;
        t[ty + s * 8][tx] = (p < Pp && h < Hh) ? hW[(size_t)p * Hh + h] : 0.0f;
    }
    __syncthreads();
    #pragma unroll
    for (int s = 0; s < 4; ++s) {
        const int h = h0 + ty + s * 8, p = p0 + tx;
        float v = t[tx][ty + s * 8];
        if (h == Hh) v = (p < Pp) ? bh[p] : (p == Pp ? 1.0f : 0.0f);
        else if (h > Hh) v = 0.0f;
        out[(size_t)h * KA + p] = (bf16_t)v;
    }
}

// ---------------------------------------------------------------------------
// fill T1taug col stripe [j][2048..2079]: col 2048 = (j==768 ? bil_b[r] : 0)
// ---------------------------------------------------------------------------
__global__ __launch_bounds__(256) void fill_T1cols(
    const float* __restrict__ bil_b, bf16_t* __restrict__ T1)
{
    const int idx = blockIdx.x * 256 + threadIdx.x;
    if (idx >= Rr * HA) return;
    const int r = idx / HA, j = idx % HA;
    bf16_t* p = T1 + (size_t)r * HA * KA + (size_t)j * KA + Pp;
    p[0] = (bf16_t)(j == Hh ? bil_b[r] : 0.0f);
    #pragma unroll
    for (int e = 1; e < 32; ++e) p[e] = (bf16_t)0.0f;
}

// ---------------------------------------------------------------------------
// r-MERGED 128(M)x64(N)x3(R) bf16 NT GEMM, 512 THREADS (8 waves), BK=32,
// dbuf LDS (for T1).  The R5 r-merge cut staged bytes 516->287 MB but halved
// waves/CU (3.5) and T1 regressed; this keeps the byte cut AND the proven
// ~8-10 waves/CU concurrency via 8-wave blocks: 224 blocks x 8 waves =
// 1 block/CU.  Staging per wave: 2-3 issues/step (R4-like drain length).
// Wave grid 4m x 2n, each wave 32m x 32n x 3r -> 12 MFMA/step.
//   C[r][m,n] = sum_k A[m,k] * B[r][n,k];  T1[r] = tWaug @ bilWh[r]^T
// grid 224 linear; XCD swizzle 224 = 8*28.  LDS 40 KB.
// ---------------------------------------------------------------------------
__global__ __launch_bounds__(512) void gemm_nt3_128x64_w8(
    const bf16_t* __restrict__ A, int lda,
    const bf16_t* __restrict__ B, int ldb, size_t sB,
    bf16_t* __restrict__ C, int ldc, size_t sC, int K)
{
    // XCD swizzle: each XCD owns 28 consecutive wgids = 4 n-tiles x 7 m-tiles
    const int orig = blockIdx.x;
    const int wgid = (orig & 7) * 28 + (orig >> 3);
    const int n0 = (wgid / 7) * 64;
    const int m0 = (wgid % 7) * 128;

    __shared__ bf16_t As[2][128 * 32];       // 8 KB per buf
    __shared__ bf16_t Bs[2][Rr * 64 * 32];   // 12 KB per buf

    const int tid = threadIdx.x;
    const int w = tid >> 6;      // 0..7
    const int l = tid & 63;

    // A staging (8 KB, ONE issue over 8 waves): row = w*16 + l/4, col8 = l&3
    const bf16_t* ga = A + (size_t)(m0 + (w << 4) + (l >> 2)) * lda + ((l & 3) << 3);
    // B staging (12 KB = 3 x 4KB): issue1 (8 waves) covers r = w>>2
    // rows (w&3)*16 + l/4; issue2 (waves 0-3) covers r=2 rows w*16 + l/4.
    const bf16_t* gb1 = B + (size_t)(w >> 2) * sB
                      + (size_t)(n0 + ((w & 3) << 4) + (l >> 2)) * ldb + ((l & 3) << 3);
    const bf16_t* gb2 = B + 2 * sB
                      + (size_t)(n0 + (w << 4) + (l >> 2)) * ldb + ((l & 3) << 3);

    const int wm = (w >> 1) << 5;    // wave M-offset: 0/32/64/96
    const int wn = (w & 1) << 5;     // wave N-offset: 0/32
    const int fr = l & 15;
    const int fq = (l >> 4) << 3;

    floatx4 acc[Rr][2][2] = {};

    {
        gld_lds16(ga,  (char*)As[0] + (w << 10));
        gld_lds16(gb1, (char*)Bs[0] + (w << 10));
        if (w < 4) gld_lds16(gb2, (char*)Bs[0] + 8192 + (w << 10));
        ga += 32; gb1 += 32; gb2 += 32;
    }

    const int steps = K >> 5;   // 64
    for (int k = 0; k < steps; ++k) {
        __syncthreads();
        const int cur = k & 1;
        if (k + 1 < steps) {
            gld_lds16(ga,  (char*)As[cur ^ 1] + (w << 10));
            gld_lds16(gb1, (char*)Bs[cur ^ 1] + (w << 10));
            if (w < 4) gld_lds16(gb2, (char*)Bs[cur ^ 1] + 8192 + (w << 10));
            ga += 32; gb1 += 32; gb2 += 32;
        }

        bf16x8 a[2];
        #pragma unroll
        for (int i = 0; i < 2; ++i)
            a[i] = *(const bf16x8*)&As[cur][(wm + i * 16 + fr) * 32 + fq];
        #pragma unroll
        for (int r = 0; r < Rr; ++r) {
            bf16x8 b[2];
            #pragma unroll
            for (int j = 0; j < 2; ++j)
                b[j] = *(const bf16x8*)&Bs[cur][r * 2048 + (wn + j * 16 + fr) * 32 + fq];
            #pragma unroll
            for (int i = 0; i < 2; ++i)
                #pragma unroll
                for (int j = 0; j < 2; ++j)
                    acc[r][i][j] = __builtin_amdgcn_mfma_f32_16x16x32_bf16(a[i], b[j], acc[r][i][j], 0, 0, 0);
        }
    }

    const int em = m0 + wm + ((l >> 4) << 2);
    const int en = n0 + wn + (l & 15);
    #pragma unroll
    for (int r = 0; r < Rr; ++r)
        #pragma unroll
        for (int i = 0; i < 2; ++i)
            #pragma unroll
            for (int j = 0; j < 2; ++j)
                #pragma unroll
                for (int rg = 0; rg < 4; ++rg)
                    C[(size_t)r * sC + (size_t)(em + i * 16 + rg) * ldc + en + j * 16]
                        = (bf16_t)acc[r][i][j][rg];
}

// ---------------------------------------------------------------------------
// 64x64-tile bf16 NT GEMM, dbuf LDS (for Bop). R4 body + bijective XCD
// swizzle (588 = 8*73 + 4): each XCD runs ~73 consecutive wgids = single r,
// ~5 m-tiles, all n -> B (hWaug 3.7MB) L2-resident per XCD.
// grid (14, 14, 3).
// ---------------------------------------------------------------------------
__global__ __launch_bounds__(256) void gemm_nt_64(
    const bf16_t* __restrict__ A, int lda, size_t sA,
    const bf16_t* __restrict__ B, int ldb, size_t sB,
    bf16_t* __restrict__ C, int ldc, size_t sC, int K)
{
    // bijective XCD swizzle for nwg=588: q=73, rem=4
    const int orig = (blockIdx.z * 14 + blockIdx.y) * 14 + blockIdx.x;
    const int xcd = orig & 7, idx = orig >> 3;
    const int wgid = (xcd < 4 ? xcd * 74 : 296 + (xcd - 4) * 73) + idx;
    const int r    = wgid / 196;
    const int rest = wgid % 196;
    const int m0 = (rest / 14) * 64;
    const int n0 = (rest % 14) * 64;
    A += (size_t)r * sA;
    B += (size_t)r * sB;
    C += (size_t)r * sC;

    __shared__ bf16_t As[2][64 * 32];
    __shared__ bf16_t Bs[2][64 * 32];

    const int tid = threadIdx.x;
    const int w = tid >> 6;
    const int l = tid & 63;

    const bf16_t* ga = A + (size_t)(m0 + (tid >> 2)) * lda + ((tid & 3) << 3);
    const bf16_t* gb = B + (size_t)(n0 + (tid >> 2)) * ldb + ((tid & 3) << 3);

    const int wm = (w >> 1) << 5;
    const int wn = (w & 1) << 5;
    const int fr = l & 15;
    const int fq = (l >> 4) << 3;

    floatx4 acc[2][2] = {};

    {
        gld_lds16(ga, (char*)As[0] + (w << 10));
        gld_lds16(gb, (char*)Bs[0] + (w << 10));
        ga += 32; gb += 32;
    }

    const int steps = K >> 5;
    for (int k = 0; k < steps; ++k) {
        __syncthreads();
        const int cur = k & 1;
        if (k + 1 < steps) {
            gld_lds16(ga, (char*)As[cur ^ 1] + (w << 10));
            gld_lds16(gb, (char*)Bs[cur ^ 1] + (w << 10));
            ga += 32; gb += 32;
        }

        bf16x8 a[2], b[2];
        #pragma unroll
        for (int i = 0; i < 2; ++i) {
            a[i] = *(const bf16x8*)&As[cur][(wm + i * 16 + fr) * 32 + fq];
            b[i] = *(const bf16x8*)&Bs[cur][(wn + i * 16 + fr) * 32 + fq];
        }
        #pragma unroll
        for (int i = 0; i < 2; ++i)
            #pragma unroll
            for (int j = 0; j < 2; ++j)
                acc[i][j] = __builtin_amdgcn_mfma_f32_16x16x32_bf16(a[i], b[j], acc[i][j], 0, 0, 0);
    }

    const int em = m0 + wm + ((l >> 4) << 2);
    const int en = n0 + wn + (l & 15);
    #pragma unroll
    for (int i = 0; i < 2; ++i)
        #pragma unroll
        for (int j = 0; j < 2; ++j)
            #pragma unroll
            for (int rg = 0; rg < 4; ++rg)
                C[(size_t)(em + i * 16 + rg) * ldc + en + j * 16] = (bf16_t)acc[i][j][rg];
}

// ---------------------------------------------------------------------------
// 128x128-tile bf16 NT GEMM, dbuf LDS (for FG). R4 body + XCD swizzle
// (672 = 8*84): each XCD owns 4 m-tiles x all n -> B (Bop 4.8MB) ~L2-resident.
// grid (21, 32): x = n-tile (JA/128), y = m-tile (Mm/128).
// ---------------------------------------------------------------------------
__global__ __launch_bounds__(256) void gemm_nt_128(
    const bf16_t* __restrict__ A, int lda,
    const bf16_t* __restrict__ B, int ldb,
    bf16_t* __restrict__ C, int ldc, int K)
{
    const int orig = blockIdx.y * 21 + blockIdx.x;
    const int wgid = (orig & 7) * 84 + (orig >> 3);
    const int m0 = (wgid / 21) * 128;
    const int n0 = (wgid % 21) * 128;

    __shared__ bf16_t As[2][128 * 32];
    __shared__ bf16_t Bs[2][128 * 32];

    const int tid = threadIdx.x;
    const int w = tid >> 6;
    const int l = tid & 63;

    const int srow = (w << 4) + (l >> 2);
    const int scol = (l & 3) << 3;
    const bf16_t* ga0 = A + (size_t)(m0 + srow) * lda + scol;
    const bf16_t* ga1 = ga0 + (size_t)64 * lda;
    const bf16_t* gb0 = B + (size_t)(n0 + srow) * ldb + scol;
    const bf16_t* gb1 = gb0 + (size_t)64 * ldb;

    const int wm = (w >> 1) << 6;
    const int wn = (w & 1) << 6;
    const int fr = l & 15;
    const int fq = (l >> 4) << 3;

    floatx4 acc[4][4] = {};

    {
        char* a = (char*)As[0] + (w << 10);
        char* b = (char*)Bs[0] + (w << 10);
        gld_lds16(ga0, a); gld_lds16(ga1, a + 4096);
        gld_lds16(gb0, b); gld_lds16(gb1, b + 4096);
        ga0 += 32; ga1 += 32; gb0 += 32; gb1 += 32;
    }

    const int steps = K >> 5;
    for (int k = 0; k < steps; ++k) {
        __syncthreads();
        const int cur = k & 1;
        if (k + 1 < steps) {
            char* a = (char*)As[cur ^ 1] + (w << 10);
            char* b = (char*)Bs[cur ^ 1] + (w << 10);
            gld_lds16(ga0, a); gld_lds16(ga1, a + 4096);
            gld_lds16(gb0, b); gld_lds16(gb1, b + 4096);
            ga0 += 32; ga1 += 32; gb0 += 32; gb1 += 32;
        }

        bf16x8 a[4], b[4];
        #pragma unroll
        for (int i = 0; i < 4; ++i) {
            a[i] = *(const bf16x8*)&As[cur][(wm + i * 16 + fr) * 32 + fq];
            b[i] = *(const bf16x8*)&Bs[cur][(wn + i * 16 + fr) * 32 + fq];
        }
        #pragma unroll
        for (int i = 0; i < 4; ++i)
            #pragma unroll
            for (int j = 0; j < 4; ++j)
                acc[i][j] = __builtin_amdgcn_mfma_f32_16x16x32_bf16(a[i], b[j], acc[i][j], 0, 0, 0);
    }

    const int em = m0 + wm + ((l >> 4) << 2);
    const int en = n0 + wn + (l & 15);
    #pragma unroll
    for (int j = 0; j < 4; ++j) {
        const int n = en + j * 16;
        #pragma unroll
        for (int i = 0; i < 4; ++i) {
            #pragma unroll
            for (int rg = 0; rg < 4; ++rg)
                C[(size_t)(em + i * 16 + rg) * ldc + n] = (bf16_t)(acc[i][j][rg]);
        }
    }
}

// ---------------------------------------------------------------------------
// fused output GEMM, all 3 r per block, dbuf LDS, K=896, 512 threads.
// R4 body + XCD swizzle (256 = 8*32): each XCD owns 2 batch values ->
// FG/Faug row-slices (3.7MB) L2-resident per XCD.
// grid (4, 4, 16).
// ---------------------------------------------------------------------------
__global__ __launch_bounds__(512) void gemm_out_fused(
    const bf16_t* __restrict__ FG,    // [Mm, JA]
    const bf16_t* __restrict__ FA,    // [Mm, HA]
    float* __restrict__ OUT)
{
    const int orig = (blockIdx.z * 4 + blockIdx.y) * 4 + blockIdx.x;
    const int wgid = (orig & 7) * 32 + (orig >> 3);
    const int b  = wgid >> 4;
    const int n0 = ((wgid >> 2) & 3) * 64;
    const int m0 = (wgid & 3) * 64;

    __shared__ bf16_t S[2][4][64 * 32];  // tiles 0..2 = FG r, 3 = Faug (32KB)

    const int tid = threadIdx.x;
    const int w = tid >> 6;      // 0..7
    const int l = tid & 63;

    // staging: 16KB/step over 512 lanes = 2 issues of 16B.
    // issue i, wave w covers LDS bytes i*8192 + w*1024 + l*16
    //   -> tile = 2i + (w>>2), row = (w&3)*16 + l/4, col8 = (l&3)*8
    const int srow = ((w & 3) << 4) + (l >> 2);
    const int scol = (l & 3) << 3;
    const int t0 = w >> 2;               // issue0 tile: FG r = 0/1
    const bf16_t* g0 = FG + (size_t)(b * Nn + n0 + srow) * JA + t0 * HA + scol;
    const bf16_t* g1 = (t0 == 0)
        ? FG + (size_t)(b * Nn + n0 + srow) * JA + 2 * HA + scol   // tile2: FG r=2
        : FA + (size_t)(b * Nn + m0 + srow) * HA + scol;           // tile3: Faug

    const int n_off = (w >> 2) << 5;     // 0/32
    const int m_off = (w & 3) << 4;      // 0/16/32/48
    const int fr = l & 15;
    const int fq = (l >> 4) << 3;

    floatx4 acc[Rr][2] = {};

    {
        char* base = (char*)&S[0][0][0];
        gld_lds16(g0, base + (w << 10));        g0 += 32;
        gld_lds16(g1, base + 8192 + (w << 10)); g1 += 32;
    }

    constexpr int STEPS = HA / 32; // 28
    for (int k = 0; k < STEPS; ++k) {
        __syncthreads();
        const int cur = k & 1;
        if (k + 1 < STEPS) {
            char* base = (char*)&S[cur ^ 1][0][0];
            gld_lds16(g0, base + (w << 10));        g0 += 32;
            gld_lds16(g1, base + 8192 + (w << 10)); g1 += 32;
        }

        bf16x8 t = *(const bf16x8*)&S[cur][3][(m_off + fr) * 32 + fq];
        #pragma unroll
        for (int r = 0; r < Rr; ++r) {
            #pragma unroll
            for (int i = 0; i < 2; ++i) {
                bf16x8 a = *(const bf16x8*)&S[cur][r][(n_off + i * 16 + fr) * 32 + fq];
                acc[r][i] = __builtin_amdgcn_mfma_f32_16x16x32_bf16(a, t, acc[r][i], 0, 0, 0);
            }
        }
    }

    const int en_ = n0 + n_off + ((l >> 4) << 2);
    const int em_ = m0 + m_off + (l & 15);
    #pragma unroll
    for (int i = 0; i < 2; ++i)
        #pragma unroll
        for (int rg = 0; rg < 4; ++rg) {
            const int n = en_ + i * 16 + rg;
            float* o = OUT + (((size_t)b * Nn + n) * Nn + em_) * Rr;
            #pragma unroll
            for (int r = 0; r < Rr; ++r)
                o[r] = acc[r][i][rg];
        }
}

extern "C" void kernel_launch(void* const* d_in, const int* in_sizes, int n_in,
                              void* d_out, int out_size, void* d_ws, size_t ws_size,
                              hipStream_t stream) {
    const float* features = (const float*)d_in[0]; // [16,256,768]
    const float* head_W   = (const float*)d_in[1]; // [2048,768]
    const float* head_b   = (const float*)d_in[2]; // [2048]
    const float* tail_W   = (const float*)d_in[3]; // [2048,768]
    const float* tail_b   = (const float*)d_in[4]; // [2048]
    const float* bil_W    = (const float*)d_in[5]; // [3,2048,2048]
    const float* bil_b    = (const float*)d_in[6]; // [3]
    float* out = (float*)d_out;                    // [16,256,256,3]

    // workspace layout (bf16), total 52.76 MB.
    // Z region (26.84 MB) is time-shared:
    //   steps 0-2: bilWh (25.17 MB) lives at Z[0..]
    //   step 3+:   Bop (4.82 MB) at Z[0..]   (bilWh dead after T1)
    //   step 4+:   FG (22.02 MB) at Z[4.82MB..]
    char* ws = (char*)d_ws;
    bf16_t* Faug   = (bf16_t*)ws;  ws += (size_t)Mm * HA * 2;       // 7.34 MB
    bf16_t* tWaug  = (bf16_t*)ws;  ws += (size_t)HA * Pp * 2;       // 3.67 MB
    bf16_t* hWaug  = (bf16_t*)ws;  ws += (size_t)HA * KA * 2;       // 3.73 MB
    bf16_t* T1taug = (bf16_t*)ws;  ws += (size_t)Rr * HA * KA * 2;  // 11.18 MB
    char*   Z      = ws;
    bf16_t* bilWh  = (bf16_t*)Z;                                    // 25.17 MB (steps 0-2)
    bf16_t* Bop    = (bf16_t*)Z;                                    // 4.82 MB (step 3+)
    bf16_t* FG     = (bf16_t*)(Z + (size_t)Rr * HA * HA * 2);       // 22.02 MB (step 4+)

    // 0) bil_W -> bf16 (one streaming pass; halves T1's B staging bytes)
    cvt_bilW<<<(Rr * Pp * Pp / 8) / 256, 256, 0, stream>>>(bil_W, bilWh);

    // 1) build augmented operands (tiny/streaming)
    build_Faug<<<Mm * (HA / 4) / 256, 256, 0, stream>>>(features, Faug);
    build_tWaug<<<dim3(Pp / 32, HA / 32), dim3(32, 8), 0, stream>>>(tail_W, tail_b, tWaug);
    build_hWaug<<<dim3(KA / 32, HA / 32), dim3(32, 8), 0, stream>>>(head_W, head_b, hWaug);

    // 2) T1taug[r] [896, 2048(+32)] = tWaug [896,2048] @ bilWh[r]^T
    //    r-merged 8-wave blocks: 287 MB staged at 8 waves/CU, 224 blocks
    gemm_nt3_128x64_w8<<<dim3(224), 512, 0, stream>>>(
        tWaug, Pp,
        bilWh, Pp, (size_t)Pp * Pp,
        T1taug, KA, (size_t)HA * KA, Pp);
    fill_T1cols<<<(Rr * HA + 255) / 256, 256, 0, stream>>>(bil_b, T1taug);

    // 3) Bop[r] [896, 896] = T1taug[r] [896,2080] @ hWaug^T [896,2080]
    //    (writes over dead bilWh region)
    gemm_nt_64<<<dim3(HA / 64, HA / 64, Rr), 256, 0, stream>>>(
        T1taug, KA, (size_t)HA * KA,
        hWaug, KA, 0,
        Bop, HA, (size_t)HA * HA, KA);

    // 4) FG [4096, 2688] = Faug [4096,896] @ Bop^T [2688,896]
    gemm_nt_128<<<dim3(JA / 128, Mm / 128), 256, 0, stream>>>(
        Faug, HA,
        Bop, HA,
        FG, JA, HA);

    // 5) fused output GEMM over all r (K=896, biases already folded in)
    gemm_out_fused<<<dim3(Nn / 64, Nn / 64, Bb), 512, 0, stream>>>(FG, Faug, out);
}

// Round 8
// 234.686 us; speedup vs baseline: 1.0632x; 1.0632x over previous
//
#include <hip/hip_runtime.h>

// Problem constants
constexpr int Bb = 16;      // batch
constexpr int Nn = 256;     // regions
constexpr int Hh = 768;     // hidden
constexpr int Pp = 2048;    // proj dim
constexpr int Rr = 3;       // relation types
constexpr int Mm = Bb * Nn; // 4096 flattened rows
constexpr int HA = 896;     // augmented hidden (768 + 1 bias row + pad)
constexpr int KA = 2080;    // augmented K for Bop GEMM (2048 + 32)
constexpr int JA = Rr * HA; // 2688

typedef __bf16 bf16_t;
typedef __bf16 bf16x8 __attribute__((ext_vector_type(8)));
typedef __bf16 bf16x4 __attribute__((ext_vector_type(4)));
typedef float  floatx4 __attribute__((ext_vector_type(4)));

// async global->LDS, 16B per lane; LDS dest = wave-uniform base + lane*16
__device__ __forceinline__ void gld_lds16(const void* g, void* l) {
    __builtin_amdgcn_global_load_lds(
        (__attribute__((address_space(1))) void*)g,
        (__attribute__((address_space(3))) void*)l,
        16, 0, 0);
}

// ---------------------------------------------------------------------------
// MEGA-PREP: one kernel fusing 5 independent streaming passes (block-range
// dispatch). Cuts launch count 9 -> 5; all parts are BW-bound and mutually
// independent, so they tile the GPU together instead of serializing with
// per-launch ramp-up/drain.
//   [0, 6144):          cvt_bilW   fp32->bf16, 8 elems/thread
//   [6144, 9728):       build_Faug
//   [9728, 11520):      build_tWaug (32x32 LDS transpose tiles)
//   [11520, 13340):     build_hWaug
//   [13340, 13351):     fill_T1cols (T1 cols 2048..2079 — DISJOINT from the
//                       T1 GEMM's cols 0..2047, so it can run before it)
// ---------------------------------------------------------------------------
constexpr int CVT_BLOCKS  = (Rr * Pp * Pp / 8) / 256;  // 6144
constexpr int FAUG_BLOCKS = Mm * (HA / 4) / 256;       // 3584
constexpr int TW_BX = Pp / 32, TW_BY = HA / 32;        // 64 x 28 = 1792
constexpr int HW_BX = KA / 32, HW_BY = HA / 32;        // 65 x 28 = 1820
constexpr int FILL_BLOCKS = (Rr * HA + 255) / 256;     // 11
constexpr int PREP_BLOCKS = CVT_BLOCKS + FAUG_BLOCKS
                          + TW_BX * TW_BY + HW_BX * HW_BY + FILL_BLOCKS;

__global__ __launch_bounds__(256) void prep_all(
    const float* __restrict__ bil_W, bf16_t* __restrict__ bilWh,
    const float* __restrict__ F,     bf16_t* __restrict__ Faug,
    const float* __restrict__ tW, const float* __restrict__ bt, bf16_t* __restrict__ tWaug,
    const float* __restrict__ hW, const float* __restrict__ bh, bf16_t* __restrict__ hWaug,
    const float* __restrict__ bil_b, bf16_t* __restrict__ T1)
{
    __shared__ float t[32][33];
    int bid = blockIdx.x;
    const int tid = threadIdx.x;

    if (bid < CVT_BLOCKS) {             // ---- cvt_bilW ----
        const size_t i = (size_t)bid * 256 + tid;
        const float4 v0 = ((const float4*)bil_W)[2 * i];
        const float4 v1 = ((const float4*)bil_W)[2 * i + 1];
        bf16x8 o = { (bf16_t)v0.x, (bf16_t)v0.y, (bf16_t)v0.z, (bf16_t)v0.w,
                     (bf16_t)v1.x, (bf16_t)v1.y, (bf16_t)v1.z, (bf16_t)v1.w };
        ((bf16x8*)bilWh)[i] = o;
        return;
    }
    bid -= CVT_BLOCKS;

    if (bid < FAUG_BLOCKS) {            // ---- build_Faug ----
        const int idx = bid * 256 + tid;
        const int n = idx / (HA / 4), c4 = idx % (HA / 4);
        const int h = c4 * 4;
        bf16x4 o;
        if (h < Hh) {
            float4 v = *(const float4*)(F + (size_t)n * Hh + h);
            o = { (bf16_t)v.x, (bf16_t)v.y, (bf16_t)v.z, (bf16_t)v.w };
        } else {
            #pragma unroll
            for (int e = 0; e < 4; ++e) o[e] = (bf16_t)((h + e == Hh) ? 1.0f : 0.0f);
        }
        *(bf16x4*)(Faug + (size_t)n * HA + h) = o;
        return;
    }
    bid -= FAUG_BLOCKS;

    const int tx = tid & 31, ty = tid >> 5;    // 32x8 layout for transposes

    if (bid < TW_BX * TW_BY) {          // ---- build_tWaug ----
        const int q0 = (bid % TW_BX) * 32, j0 = (bid / TW_BX) * 32;
        #pragma unroll
        for (int s = 0; s < 4; ++s) {
            const int q = q0 + ty + s * 8, j = j0 + tx;
            t[ty + s * 8][tx] = (j < Hh) ? tW[(size_t)q * Hh + j] : 0.0f;
        }
        __syncthreads();
        #pragma unroll
        for (int s = 0; s < 4; ++s) {
            const int j = j0 + ty + s * 8, q = q0 + tx;
            float v = t[tx][ty + s * 8];
            if (j == Hh) v = bt[q];
            else if (j > Hh) v = 0.0f;
            tWaug[(size_t)j * Pp + q] = (bf16_t)v;
        }
        return;
    }
    bid -= TW_BX * TW_BY;

    if (bid < HW_BX * HW_BY) {          // ---- build_hWaug ----
        const int p0 = (bid % HW_BX) * 32, h0 = (bid / HW_BX) * 32;
        #pragma unroll
        for (int s = 0; s < 4; ++s) {
            const int p = p0 + ty + s * 8, h = h0 + tx;
            t[ty + s * 8][tx] = (p < Pp && h < Hh) ? hW[(size_t)p * Hh + h] : 0.0f;
        }
        __syncthreads();
        #pragma unroll
        for (int s = 0; s < 4; ++s) {
            const int h = h0 + ty + s * 8, p = p0 + tx;
            float v = t[tx][ty + s * 8];
            if (h == Hh) v = (p < Pp) ? bh[p] : (p == Pp ? 1.0f : 0.0f);
            else if (h > Hh) v = 0.0f;
            hWaug[(size_t)h * KA + p] = (bf16_t)v;
        }
        return;
    }
    bid -= HW_BX * HW_BY;

    {                                   // ---- fill_T1cols ----
        const int idx = bid * 256 + tid;
        if (idx >= Rr * HA) return;
        const int r = idx / HA, j = idx % HA;
        bf16_t* p = T1 + (size_t)r * HA * KA + (size_t)j * KA + Pp;
        p[0] = (bf16_t)(j == Hh ? bil_b[r] : 0.0f);
        #pragma unroll
        for (int e = 1; e < 32; ++e) p[e] = (bf16_t)0.0f;
    }
}

// ---------------------------------------------------------------------------
// 128(M)x64(N)-tile bf16 NT GEMM, BK=32, dbuf LDS (for T1). R6 body (known
// 49.1 us): 672 blocks = 2.6/CU — the proven concurrency regime. R7's 8-wave
// r-merged variant (224 blocks = 0.875/CU) proved that INDEPENDENT blocks,
// not waves within a block, are what hide the per-step vmcnt drain.
//   C[m,n] = sum_k A[m,k] * B[r][n,k];  T1 = tWaug @ bilWh[r]^T
// XCD swizzle: 672 = 8*84.
// ---------------------------------------------------------------------------
__global__ __launch_bounds__(256) void gemm_nt_128x64(
    const bf16_t* __restrict__ A, int lda,
    const bf16_t* __restrict__ B, int ldb, size_t sB,
    bf16_t* __restrict__ C, int ldc, size_t sC, int K)
{
    const int orig = blockIdx.y * 21 + blockIdx.x;
    const int wgid = (orig & 7) * 84 + (orig >> 3);
    const int n0 = (wgid / 21) * 64;
    const int mr = wgid % 21;
    const int m0 = (mr / 3) * 128;
    const int r  = mr % 3;
    B += (size_t)r * sB;
    C += (size_t)r * sC;

    __shared__ bf16_t As[2][128 * 32];   // 8 KB per buf
    __shared__ bf16_t Bs[2][64 * 32];    // 4 KB per buf

    const int tid = threadIdx.x;
    const int w = tid >> 6;
    const int l = tid & 63;

    const bf16_t* ga0 = A + (size_t)(m0 + (w << 4) + (l >> 2)) * lda + ((l & 3) << 3);
    const bf16_t* ga1 = ga0 + (size_t)64 * lda;
    const bf16_t* gb = B + (size_t)(n0 + (tid >> 2)) * ldb + ((tid & 3) << 3);

    const int wm = (w >> 1) << 6;    // wave M-offset: 0/64
    const int wn = (w & 1) << 5;     // wave N-offset: 0/32
    const int fr = l & 15;
    const int fq = (l >> 4) << 3;

    floatx4 acc[4][2] = {};

    {
        gld_lds16(ga0, (char*)As[0] + (w << 10));
        gld_lds16(ga1, (char*)As[0] + 4096 + (w << 10));
        gld_lds16(gb,  (char*)Bs[0] + (w << 10));
        ga0 += 32; ga1 += 32; gb += 32;
    }

    const int steps = K >> 5;   // 64
    for (int k = 0; k < steps; ++k) {
        __syncthreads();
        const int cur = k & 1;
        if (k + 1 < steps) {
            gld_lds16(ga0, (char*)As[cur ^ 1] + (w << 10));
            gld_lds16(ga1, (char*)As[cur ^ 1] + 4096 + (w << 10));
            gld_lds16(gb,  (char*)Bs[cur ^ 1] + (w << 10));
            ga0 += 32; ga1 += 32; gb += 32;
        }

        bf16x8 a[4], b[2];
        #pragma unroll
        for (int i = 0; i < 4; ++i)
            a[i] = *(const bf16x8*)&As[cur][(wm + i * 16 + fr) * 32 + fq];
        #pragma unroll
        for (int j = 0; j < 2; ++j)
            b[j] = *(const bf16x8*)&Bs[cur][(wn + j * 16 + fr) * 32 + fq];
        #pragma unroll
        for (int i = 0; i < 4; ++i)
            #pragma unroll
            for (int j = 0; j < 2; ++j)
                acc[i][j] = __builtin_amdgcn_mfma_f32_16x16x32_bf16(a[i], b[j], acc[i][j], 0, 0, 0);
    }

    const int em = m0 + wm + ((l >> 4) << 2);
    const int en = n0 + wn + (l & 15);
    #pragma unroll
    for (int i = 0; i < 4; ++i)
        #pragma unroll
        for (int j = 0; j < 2; ++j)
            #pragma unroll
            for (int rg = 0; rg < 4; ++rg)
                C[(size_t)(em + i * 16 + rg) * ldc + en + j * 16] = (bf16_t)acc[i][j][rg];
}

// ---------------------------------------------------------------------------
// 64x64-tile bf16 NT GEMM, dbuf LDS (for Bop). R6 body: bijective XCD
// swizzle (588 = 8*73 + 4). grid (14, 14, 3).
// ---------------------------------------------------------------------------
__global__ __launch_bounds__(256) void gemm_nt_64(
    const bf16_t* __restrict__ A, int lda, size_t sA,
    const bf16_t* __restrict__ B, int ldb, size_t sB,
    bf16_t* __restrict__ C, int ldc, size_t sC, int K)
{
    const int orig = (blockIdx.z * 14 + blockIdx.y) * 14 + blockIdx.x;
    const int xcd = orig & 7, idx = orig >> 3;
    const int wgid = (xcd < 4 ? xcd * 74 : 296 + (xcd - 4) * 73) + idx;
    const int r    = wgid / 196;
    const int rest = wgid % 196;
    const int m0 = (rest / 14) * 64;
    const int n0 = (rest % 14) * 64;
    A += (size_t)r * sA;
    B += (size_t)r * sB;
    C += (size_t)r * sC;

    __shared__ bf16_t As[2][64 * 32];
    __shared__ bf16_t Bs[2][64 * 32];

    const int tid = threadIdx.x;
    const int w = tid >> 6;
    const int l = tid & 63;

    const bf16_t* ga = A + (size_t)(m0 + (tid >> 2)) * lda + ((tid & 3) << 3);
    const bf16_t* gb = B + (size_t)(n0 + (tid >> 2)) * ldb + ((tid & 3) << 3);

    const int wm = (w >> 1) << 5;
    const int wn = (w & 1) << 5;
    const int fr = l & 15;
    const int fq = (l >> 4) << 3;

    floatx4 acc[2][2] = {};

    {
        gld_lds16(ga, (char*)As[0] + (w << 10));
        gld_lds16(gb, (char*)Bs[0] + (w << 10));
        ga += 32; gb += 32;
    }

    const int steps = K >> 5;
    for (int k = 0; k < steps; ++k) {
        __syncthreads();
        const int cur = k & 1;
        if (k + 1 < steps) {
            gld_lds16(ga, (char*)As[cur ^ 1] + (w << 10));
            gld_lds16(gb, (char*)Bs[cur ^ 1] + (w << 10));
            ga += 32; gb += 32;
        }

        bf16x8 a[2], b[2];
        #pragma unroll
        for (int i = 0; i < 2; ++i) {
            a[i] = *(const bf16x8*)&As[cur][(wm + i * 16 + fr) * 32 + fq];
            b[i] = *(const bf16x8*)&Bs[cur][(wn + i * 16 + fr) * 32 + fq];
        }
        #pragma unroll
        for (int i = 0; i < 2; ++i)
            #pragma unroll
            for (int j = 0; j < 2; ++j)
                acc[i][j] = __builtin_amdgcn_mfma_f32_16x16x32_bf16(a[i], b[j], acc[i][j], 0, 0, 0);
    }

    const int em = m0 + wm + ((l >> 4) << 2);
    const int en = n0 + wn + (l & 15);
    #pragma unroll
    for (int i = 0; i < 2; ++i)
        #pragma unroll
        for (int j = 0; j < 2; ++j)
            #pragma unroll
            for (int rg = 0; rg < 4; ++rg)
                C[(size_t)(em + i * 16 + rg) * ldc + en + j * 16] = (bf16_t)acc[i][j][rg];
}

// ---------------------------------------------------------------------------
// 128x128-tile bf16 NT GEMM, dbuf LDS (for FG). R6 body: XCD swizzle
// (672 = 8*84). grid (21, 32).
// ---------------------------------------------------------------------------
__global__ __launch_bounds__(256) void gemm_nt_128(
    const bf16_t* __restrict__ A, int lda,
    const bf16_t* __restrict__ B, int ldb,
    bf16_t* __restrict__ C, int ldc, int K)
{
    const int orig = blockIdx.y * 21 + blockIdx.x;
    const int wgid = (orig & 7) * 84 + (orig >> 3);
    const int m0 = (wgid / 21) * 128;
    const int n0 = (wgid % 21) * 128;

    __shared__ bf16_t As[2][128 * 32];
    __shared__ bf16_t Bs[2][128 * 32];

    const int tid = threadIdx.x;
    const int w = tid >> 6;
    const int l = tid & 63;

    const int srow = (w << 4) + (l >> 2);
    const int scol = (l & 3) << 3;
    const bf16_t* ga0 = A + (size_t)(m0 + srow) * lda + scol;
    const bf16_t* ga1 = ga0 + (size_t)64 * lda;
    const bf16_t* gb0 = B + (size_t)(n0 + srow) * ldb + scol;
    const bf16_t* gb1 = gb0 + (size_t)64 * ldb;

    const int wm = (w >> 1) << 6;
    const int wn = (w & 1) << 6;
    const int fr = l & 15;
    const int fq = (l >> 4) << 3;

    floatx4 acc[4][4] = {};

    {
        char* a = (char*)As[0] + (w << 10);
        char* b = (char*)Bs[0] + (w << 10);
        gld_lds16(ga0, a); gld_lds16(ga1, a + 4096);
        gld_lds16(gb0, b); gld_lds16(gb1, b + 4096);
        ga0 += 32; ga1 += 32; gb0 += 32; gb1 += 32;
    }

    const int steps = K >> 5;
    for (int k = 0; k < steps; ++k) {
        __syncthreads();
        const int cur = k & 1;
        if (k + 1 < steps) {
            char* a = (char*)As[cur ^ 1] + (w << 10);
            char* b = (char*)Bs[cur ^ 1] + (w << 10);
            gld_lds16(ga0, a); gld_lds16(ga1, a + 4096);
            gld_lds16(gb0, b); gld_lds16(gb1, b + 4096);
            ga0 += 32; ga1 += 32; gb0 += 32; gb1 += 32;
        }

        bf16x8 a[4], b[4];
        #pragma unroll
        for (int i = 0; i < 4; ++i) {
            a[i] = *(const bf16x8*)&As[cur][(wm + i * 16 + fr) * 32 + fq];
            b[i] = *(const bf16x8*)&Bs[cur][(wn + i * 16 + fr) * 32 + fq];
        }
        #pragma unroll
        for (int i = 0; i < 4; ++i)
            #pragma unroll
            for (int j = 0; j < 4; ++j)
                acc[i][j] = __builtin_amdgcn_mfma_f32_16x16x32_bf16(a[i], b[j], acc[i][j], 0, 0, 0);
    }

    const int em = m0 + wm + ((l >> 4) << 2);
    const int en = n0 + wn + (l & 15);
    #pragma unroll
    for (int j = 0; j < 4; ++j) {
        const int n = en + j * 16;
        #pragma unroll
        for (int i = 0; i < 4; ++i) {
            #pragma unroll
            for (int rg = 0; rg < 4; ++rg)
                C[(size_t)(em + i * 16 + rg) * ldc + n] = (bf16_t)(acc[i][j][rg]);
        }
    }
}

// ---------------------------------------------------------------------------
// fused output GEMM, all 3 r per block, dbuf LDS, K=896, 512 threads.
// R6 body: XCD swizzle (256 = 8*32). grid (4, 4, 16).
// ---------------------------------------------------------------------------
__global__ __launch_bounds__(512) void gemm_out_fused(
    const bf16_t* __restrict__ FG,    // [Mm, JA]
    const bf16_t* __restrict__ FA,    // [Mm, HA]
    float* __restrict__ OUT)
{
    const int orig = (blockIdx.z * 4 + blockIdx.y) * 4 + blockIdx.x;
    const int wgid = (orig & 7) * 32 + (orig >> 3);
    const int b  = wgid >> 4;
    const int n0 = ((wgid >> 2) & 3) * 64;
    const int m0 = (wgid & 3) * 64;

    __shared__ bf16_t S[2][4][64 * 32];  // tiles 0..2 = FG r, 3 = Faug (32KB)

    const int tid = threadIdx.x;
    const int w = tid >> 6;      // 0..7
    const int l = tid & 63;

    const int srow = ((w & 3) << 4) + (l >> 2);
    const int scol = (l & 3) << 3;
    const int t0 = w >> 2;               // issue0 tile: FG r = 0/1
    const bf16_t* g0 = FG + (size_t)(b * Nn + n0 + srow) * JA + t0 * HA + scol;
    const bf16_t* g1 = (t0 == 0)
        ? FG + (size_t)(b * Nn + n0 + srow) * JA + 2 * HA + scol   // tile2: FG r=2
        : FA + (size_t)(b * Nn + m0 + srow) * HA + scol;           // tile3: Faug

    const int n_off = (w >> 2) << 5;     // 0/32
    const int m_off = (w & 3) << 4;      // 0/16/32/48
    const int fr = l & 15;
    const int fq = (l >> 4) << 3;

    floatx4 acc[Rr][2] = {};

    {
        char* base = (char*)&S[0][0][0];
        gld_lds16(g0, base + (w << 10));        g0 += 32;
        gld_lds16(g1, base + 8192 + (w << 10)); g1 += 32;
    }

    constexpr int STEPS = HA / 32; // 28
    for (int k = 0; k < STEPS; ++k) {
        __syncthreads();
        const int cur = k & 1;
        if (k + 1 < STEPS) {
            char* base = (char*)&S[cur ^ 1][0][0];
            gld_lds16(g0, base + (w << 10));        g0 += 32;
            gld_lds16(g1, base + 8192 + (w << 10)); g1 += 32;
        }

        bf16x8 t = *(const bf16x8*)&S[cur][3][(m_off + fr) * 32 + fq];
        #pragma unroll
        for (int r = 0; r < Rr; ++r) {
            #pragma unroll
            for (int i = 0; i < 2; ++i) {
                bf16x8 a = *(const bf16x8*)&S[cur][r][(n_off + i * 16 + fr) * 32 + fq];
                acc[r][i] = __builtin_amdgcn_mfma_f32_16x16x32_bf16(a, t, acc[r][i], 0, 0, 0);
            }
        }
    }

    const int en_ = n0 + n_off + ((l >> 4) << 2);
    const int em_ = m0 + m_off + (l & 15);
    #pragma unroll
    for (int i = 0; i < 2; ++i)
        #pragma unroll
        for (int rg = 0; rg < 4; ++rg) {
            const int n = en_ + i * 16 + rg;
            float* o = OUT + (((size_t)b * Nn + n) * Nn + em_) * Rr;
            #pragma unroll
            for (int r = 0; r < Rr; ++r)
                o[r] = acc[r][i][rg];
        }
}

extern "C" void kernel_launch(void* const* d_in, const int* in_sizes, int n_in,
                              void* d_out, int out_size, void* d_ws, size_t ws_size,
                              hipStream_t stream) {
    const float* features = (const float*)d_in[0]; // [16,256,768]
    const float* head_W   = (const float*)d_in[1]; // [2048,768]
    const float* head_b   = (const float*)d_in[2]; // [2048]
    const float* tail_W   = (const float*)d_in[3]; // [2048,768]
    const float* tail_b   = (const float*)d_in[4]; // [2048]
    const float* bil_W    = (const float*)d_in[5]; // [3,2048,2048]
    const float* bil_b    = (const float*)d_in[6]; // [3]
    float* out = (float*)d_out;                    // [16,256,256,3]

    // workspace layout (bf16), total 52.76 MB.
    // Z region (26.84 MB) is time-shared:
    //   steps 0-1: bilWh (25.17 MB) lives at Z[0..]
    //   step 2+:   Bop (4.82 MB) at Z[0..]   (bilWh dead after T1)
    //   step 3+:   FG (22.02 MB) at Z[4.82MB..]
    char* ws = (char*)d_ws;
    bf16_t* Faug   = (bf16_t*)ws;  ws += (size_t)Mm * HA * 2;       // 7.34 MB
    bf16_t* tWaug  = (bf16_t*)ws;  ws += (size_t)HA * Pp * 2;       // 3.67 MB
    bf16_t* hWaug  = (bf16_t*)ws;  ws += (size_t)HA * KA * 2;       // 3.73 MB
    bf16_t* T1taug = (bf16_t*)ws;  ws += (size_t)Rr * HA * KA * 2;  // 11.18 MB
    char*   Z      = ws;
    bf16_t* bilWh  = (bf16_t*)Z;                                    // 25.17 MB (prep+T1)
    bf16_t* Bop    = (bf16_t*)Z;                                    // 4.82 MB (step 2+)
    bf16_t* FG     = (bf16_t*)(Z + (size_t)Rr * HA * HA * 2);       // 22.02 MB (step 3+)

    // 0) fused prep: cvt_bilW + build_Faug + build_tWaug + build_hWaug +
    //    fill_T1cols (T1 cols 2048.. are disjoint from the T1 GEMM's writes)
    prep_all<<<PREP_BLOCKS, 256, 0, stream>>>(
        bil_W, bilWh, features, Faug,
        tail_W, tail_b, tWaug,
        head_W, head_b, hWaug,
        bil_b, T1taug);

    // 1) T1taug[r] [896, 2048(+32)] = tWaug [896,2048] @ bilWh[r]^T
    gemm_nt_128x64<<<dim3(21, 32), 256, 0, stream>>>(
        tWaug, Pp,
        bilWh, Pp, (size_t)Pp * Pp,
        T1taug, KA, (size_t)HA * KA, Pp);

    // 2) Bop[r] [896, 896] = T1taug[r] [896,2080] @ hWaug^T [896,2080]
    //    (writes over dead bilWh region)
    gemm_nt_64<<<dim3(HA / 64, HA / 64, Rr), 256, 0, stream>>>(
        T1taug, KA, (size_t)HA * KA,
        hWaug, KA, 0,
        Bop, HA, (size_t)HA * HA, KA);

    // 3) FG [4096, 2688] = Faug [4096,896] @ Bop^T [2688,896]
    gemm_nt_128<<<dim3(JA / 128, Mm / 128), 256, 0, stream>>>(
        Faug, HA,
        Bop, HA,
        FG, JA, HA);

    // 4) fused output GEMM over all r (K=896, biases already folded in)
    gemm_out_fused<<<dim3(Nn / 64, Nn / 64, Bb), 512, 0, stream>>>(FG, Faug, out);
}